// Round 7
// baseline (219.588 us; speedup 1.0000x reference)
//
#include <hip/hip_runtime.h>
#include <cmath>

#define BATCH 32768
#define SROW  66    // v2f stride per radix-8 row (padding breaks 8-way bank conflicts)
#define ROWS  8     // rows per wave (streamed)

typedef float v2f __attribute__((ext_vector_type(2)));

__device__ __forceinline__ v2f mkc(float r, float i) { v2f t; t.x = r; t.y = i; return t; }
__device__ __forceinline__ v2f cmul(v2f a, v2f b) {
    v2f s = mkc(-a.y, a.x);
    return a * b.x + s * b.y;
}
__device__ __forceinline__ v2f cmul_mi(v2f a){ return mkc(a.y, -a.x); }                  // a * (-i)
__device__ __forceinline__ v2f cmul_w81(v2f a){ const float C=0.70710678f; return mkc(C*(a.x+a.y), C*(a.y-a.x)); }
__device__ __forceinline__ v2f cmul_w83(v2f a){ const float C=0.70710678f; return mkc(C*(a.y-a.x), -C*(a.x+a.y)); }

// 8-point DFT, natural-order in/out
__device__ __forceinline__ void dft8(v2f a[8]) {
    v2f t0=a[0]+a[4], t4=a[0]-a[4];
    v2f t1=a[1]+a[5], t5=a[1]-a[5];
    v2f t2=a[2]+a[6], t6=a[2]-a[6];
    v2f t3=a[3]+a[7], t7=a[3]-a[7];
    v2f u0=t0+t2, u2=t0-t2;
    v2f u1=t1+t3, u3=cmul_mi(t1-t3);
    a[0]=u0+u1; a[4]=u0-u1; a[2]=u2+u3; a[6]=u2-u3;
    v2f v0=t4, v1=cmul_w81(t5), v2=cmul_mi(t6), v3=cmul_w83(t7);
    v2f w0=v0+v2, w2=v0-v2;
    v2f w1=v1+v3, w3=cmul_mi(v1-v3);
    a[1]=w0+w1; a[5]=w0-w1; a[3]=w2+w3; a[7]=w2-w3;
}

// ---- DPP wave-64 reductions (pure VALU, no LDS pipe) ----
__device__ __forceinline__ float wave_sum64(float x) {
    x += __int_as_float(__builtin_amdgcn_update_dpp(0, __float_as_int(x), 0x111, 0xf, 0xf, true)); // row_shr:1
    x += __int_as_float(__builtin_amdgcn_update_dpp(0, __float_as_int(x), 0x112, 0xf, 0xf, true)); // row_shr:2
    x += __int_as_float(__builtin_amdgcn_update_dpp(0, __float_as_int(x), 0x114, 0xf, 0xf, true)); // row_shr:4
    x += __int_as_float(__builtin_amdgcn_update_dpp(0, __float_as_int(x), 0x118, 0xf, 0xf, true)); // row_shr:8
    x += __int_as_float(__builtin_amdgcn_update_dpp(0, __float_as_int(x), 0x142, 0xf, 0xf, true)); // row_bcast:15
    x += __int_as_float(__builtin_amdgcn_update_dpp(0, __float_as_int(x), 0x143, 0xf, 0xf, true)); // row_bcast:31
    return __int_as_float(__builtin_amdgcn_readlane(__float_as_int(x), 63));
}
// argmax with first-occurrence (min index) tie-break; result broadcast from lane 63
__device__ __forceinline__ int wave_argmax64(float best, int besti) {
#define AM_STEP(ctrl) { \
    float ob = __int_as_float(__builtin_amdgcn_update_dpp(__float_as_int(best), __float_as_int(best), ctrl, 0xf, 0xf, false)); \
    int   oi = __builtin_amdgcn_update_dpp(besti, besti, ctrl, 0xf, 0xf, false); \
    if (ob > best || (ob == best && oi < besti)) { best = ob; besti = oi; } }
    AM_STEP(0x111) AM_STEP(0x112) AM_STEP(0x114) AM_STEP(0x118) AM_STEP(0x142) AM_STEP(0x143)
#undef AM_STEP
    return __builtin_amdgcn_readlane(besti, 63);
}

// Replicates JAX fp32 argmin(|freq - target|), first-occurrence tie-break.
__device__ __forceinline__ int nearest_bin(float fs, float target) {
    float x = target * 1024.0f / fs;
    int i0 = (int)floorf(x);
    int lo = max(0, i0 - 1), hi = min(512, i0 + 2);
    int bi = lo; float bd = 1e30f;
    for (int i = lo; i <= hi; ++i) {
        float fr = (fs * 0.5f) * ((float)i / 512.0f);
        float d = fabsf(fr - target);
        if (d < bd) { bd = d; bi = i; }
    }
    return bi;
}

// Streaming: 2 waves/block, ROWS rows per wave, register double-buffered
// prefetch (row i+1 loads in flight while row i computes). Per row: 512-pt
// complex FFT of packed even/odd samples (radix 8x8x8, two b64 LDS
// transposes), Parseval total, rfft combine only for in-band regs (t=0,1),
// DPP reductions. All twiddle chains hoisted out of the row loop.
__global__ __launch_bounds__(128, 4) void fft_loss_kernel(
    const float* __restrict__ preds, const float* __restrict__ Fs,
    float* __restrict__ wavepartial)
{
    __shared__ v2f lds[2][8 * SROW];   // 8448 B/block

    const int tid  = threadIdx.x;
    const int wv   = tid >> 6;
    const int lane = tid & 63;
    const int wave_id = blockIdx.x * 2 + wv;
    const size_t row0 = (size_t)wave_id * ROWS;

    v2f* sm = lds[wv];
    const v2f* xbase = reinterpret_cast<const v2f*>(preds) + row0 * 512;

    // ---- hoisted per-lane twiddles (loop-invariant) ----
    const int rB = lane & 7, m0 = lane >> 3, sC = lane >> 3;
    const int pl = (64 - lane) & 63;          // combine partner lane
    v2f w1,w2,w3,w4,w5,w6,w7;                 // W_512^{r*lane}
    {
        float sb, cb; __sincosf(-0.012271846f * (float)lane, &sb, &cb);
        w1 = mkc(cb, sb);
        w2 = cmul(w1,w1); w3 = cmul(w2,w1); w4 = cmul(w2,w2);
        w5 = cmul(w3,w2); w6 = cmul(w3,w3); w7 = cmul(w4,w3);
    }
    v2f b1,b2,b3,b4,b5,b6,b7;                 // W_64^{s*m0}
    {
        float sb, cb; __sincosf(-0.09817477f * (float)m0, &sb, &cb);
        b1 = mkc(cb, sb);
        b2 = cmul(b1,b1); b3 = cmul(b2,b1); b4 = cmul(b2,b2);
        b5 = cmul(b3,b2); b6 = cmul(b3,b3); b7 = cmul(b4,b3);
    }
    float wk0x, wk0y, wk1x, wk1y;             // W_1024^lane, W_1024^{lane+64}
    {
        float sk, ck; __sincosf(-0.0061359233f * (float)lane, &sk, &ck);
        wk0x = ck; wk0y = sk;
        wk1x = wk0x * 0.92387953f - wk0y * (-0.38268343f);
        wk1y = wk0x * (-0.38268343f) + wk0y * 0.92387953f;
    }

    // ---- prefetch row 0 ----
    v2f pre[8];
    float fs_next = Fs[row0];
#pragma unroll
    for (int n1 = 0; n1 < 8; ++n1) pre[n1] = xbase[n1 * 64 + lane];

    float acc = 0.f;
    for (int i = 0; i < ROWS; ++i) {
        v2f z[8];
#pragma unroll
        for (int r = 0; r < 8; ++r) z[r] = pre[r];
        const float fs = fs_next;

        // ---- issue next row's loads (consumed next iteration) ----
        const int ip = (i + 1 < ROWS) ? i + 1 : i;
        const v2f* xn = xbase + (size_t)ip * 512;
        fs_next = Fs[row0 + ip];
#pragma unroll
        for (int n1 = 0; n1 < 8; ++n1) pre[n1] = xn[n1 * 64 + lane];

        // ---- Parseval accumulators ----
        v2f sacc = mkc(0.f, 0.f), ssacc = mkc(0.f, 0.f);
#pragma unroll
        for (int r = 0; r < 8; ++r) { sacc += z[r]; ssacc += z[r] * z[r]; }

        const int left  = nearest_bin(fs, (float)(40.0 / 60.0));
        const int right = nearest_bin(fs, 3.0f);

        // ---- Stage A: lane = n0; DFT8 over n1; twiddle W_512^{r*n0} ----
        dft8(z);
        z[1]=cmul(z[1],w1); z[2]=cmul(z[2],w2); z[3]=cmul(z[3],w3);
        z[4]=cmul(z[4],w4); z[5]=cmul(z[5],w5); z[6]=cmul(z[6],w6); z[7]=cmul(z[7],w7);
#pragma unroll
        for (int r = 0; r < 8; ++r) sm[r * SROW + lane] = z[r];

        // ---- Stage B: lane = (r, m0); DFT8 over m1; twiddle W_64^{s*m0} ----
#pragma unroll
        for (int m1 = 0; m1 < 8; ++m1) z[m1] = sm[rB * SROW + 8 * m1 + m0];
        dft8(z);
        z[1]=cmul(z[1],b1); z[2]=cmul(z[2],b2); z[3]=cmul(z[3],b3);
        z[4]=cmul(z[4],b4); z[5]=cmul(z[5],b5); z[6]=cmul(z[6],b6); z[7]=cmul(z[7],b7);
#pragma unroll
        for (int s = 0; s < 8; ++s)           // XOR-swizzled 8x8 transpose
            sm[rB * SROW + 8 * m0 + ((s + m0) & 7)] = z[s];

        // ---- Stage C: lane = (r, s); DFT8 over m0 -> z[t] = Z[lane + 64 t] ----
#pragma unroll
        for (int m = 0; m < 8; ++m) z[m] = sm[rB * SROW + 8 * m + ((sC + m) & 7)];
        dft8(z);

        // ---- rfft combine for in-band registers only (t = 0,1 -> k in [0,127]) ----
        float psd[2];
        float inb = 0.f, best = -1.f;
        int besti = 1 << 30;
#pragma unroll
        for (int t = 0; t < 2; ++t) {
            v2f a = z[t];
            float px = __shfl(z[7 - t].x, pl);
            float py = __shfl(z[7 - t].y, pl);
            if (lane == 0) { px = z[(8 - t) & 7].x; py = z[(8 - t) & 7].y; }
            float wkx = (t == 0) ? wk0x : wk1x;
            float wky = (t == 0) ? wk0y : wk1y;
            float ex = 0.5f * (a.x + px), ey = 0.5f * (a.y - py);
            float dx = a.x - px,          dy = a.y + py;
            float ox = 0.5f * dy,         oy = -0.5f * dx;
            float Xr = ex + wkx * ox - wky * oy;
            float Xi = ey + wkx * oy + wky * ox;
            float v  = Xr * Xr + Xi * Xi;
            psd[t] = v;
            int k = lane + 64 * t;
            if (k >= left && k < right) {
                inb += v;
                if (v > best) { best = v; besti = k; }
            }
        }

        // total via Parseval: (1024*SS + X0^2 + X512^2)/2
        float Se = wave_sum64(sacc.x);
        float So = wave_sum64(sacc.y);
        float SS = wave_sum64(ssacc.x + ssacc.y);
        float X0 = Se + So, X512 = Se - So;
        float total = 0.5f * (1024.0f * SS + X0 * X0 + X512 * X512);

        inb = wave_sum64(inb);
        const int bbi = wave_argmax64(best, besti);

        int delta = (int)rintf(0.1f / ((fs * 0.5f) / 513.0f));
        if (delta < 1) delta = 1;
        const int lo = max(left, bbi - delta), hi = min(right, bbi + delta);
        float wsum = 0.f;
#pragma unroll
        for (int t = 0; t < 2; ++t) {
            int k = lane + 64 * t;
            if (k >= lo && k < hi) wsum += psd[t];
        }
        wsum = wave_sum64(wsum);

        float band = (total - inb) / (1e-8f + total);
        float den  = inb + 1e-8f * (float)(right - left);
        acc += band + (inb - wsum) / den;
    }

    if (lane == 0) wavepartial[wave_id] = acc;
}

__global__ __launch_bounds__(1024) void reduce_kernel(
    const float* __restrict__ wp, float* __restrict__ out)
{
    __shared__ float w[16];
    const int t = threadIdx.x;
    float acc = 0.f;
#pragma unroll
    for (int i = 0; i < 4; ++i) acc += wp[t + 1024 * i];
    acc = wave_sum64(acc);
    const int lane = t & 63, wvi = t >> 6;
    if (lane == 0) w[wvi] = acc;
    __syncthreads();
    if (t == 0) {
        float s = 0.f;
        for (int i = 0; i < 16; ++i) s += w[i];
        out[0] = s * (1.0f / (float)BATCH);
    }
}

extern "C" void kernel_launch(void* const* d_in, const int* in_sizes, int n_in,
                              void* d_out, int out_size, void* d_ws, size_t ws_size,
                              hipStream_t stream) {
    const float* preds = (const float*)d_in[0];
    const float* Fs    = (const float*)d_in[1];
    float* wp          = (float*)d_ws;      // 4096 floats = 16 KB
    float* out         = (float*)d_out;

    fft_loss_kernel<<<BATCH / (2 * ROWS), 128, 0, stream>>>(preds, Fs, wp);
    reduce_kernel<<<1, 1024, 0, stream>>>(wp, out);
}